// Round 4
// baseline (156.349 us; speedup 1.0000x reference)
//
#include <hip/hip_runtime.h>
#include <math.h>

// Self-attention: B=4, S=2048, E=1024, D=512, fp32 in/out, bf16 MFMA internally.
// R4: split-K PV (512-col chunks, fp32 atomicAdd into pre-zeroed out) kills the
//     triangular serial-K latency wall; scores on 64-row tiles (2x TLP).

typedef __attribute__((ext_vector_type(4))) float f32x4;
typedef __attribute__((ext_vector_type(16))) float f32x16;
typedef __attribute__((ext_vector_type(8))) short bf16x8;     // 8 bf16 = 4 VGPRs
typedef __attribute__((ext_vector_type(8))) unsigned short u16x8;

#define B_ 4
#define S_ 2048
#define E_ 1024
#define D_ 512

__device__ __forceinline__ unsigned short f2bf(float f) {
  unsigned u = __float_as_uint(f);
  u += 0x7fffu + ((u >> 16) & 1u);   // round-to-nearest-even
  return (unsigned short)(u >> 16);
}

__device__ __forceinline__ float bf2f(unsigned short h) {
  return __uint_as_float(((unsigned)h) << 16);
}

// ---- GEMM core: BK=32, 32x32x16 bf16 MFMA, linear LDS [row][32] (64B rows) ----

template<int ROWS, int NTHR>
__device__ __forceinline__ void stage_tile32(const unsigned short* __restrict__ g, long ld,
                                             long rowBase, int kBase,
                                             unsigned short* lds, int tid) {
  // ROWS x 32 bf16 tile; 16B/thread/call; LDS dest linear = wave-uniform + lane*16.
  constexpr int CALLS = (ROWS * 64) / (NTHR * 16);
  #pragma unroll
  for (int i = 0; i < CALLS; ++i) {
    int idx = i * NTHR + tid;
    int row = idx >> 2, c8 = (idx & 3) * 8;
    __builtin_amdgcn_global_load_lds(
      (const __attribute__((address_space(1))) void*)(g + (rowBase + row) * ld + kBase + c8),
      (__attribute__((address_space(3))) void*)(lds + idx * 8),
      16, 0, 0);
  }
}

// A frag for 32x32x16: lane reads A[row = lane&31][k = (lane>>5)*8 + 0..7]; B mirrors.
template<int MT, int NTT>
__device__ __forceinline__ void compute_tile32(const unsigned short* As, const unsigned short* Bs,
                                               int a_row0, int b_row0, int lane,
                                               f32x16 (&acc)[MT][NTT]) {
  int lr = lane & 31, lk = (lane >> 5) * 8;
  #pragma unroll
  for (int ki = 0; ki < 2; ++ki) {
    bf16x8 af[MT], bf[NTT];
    #pragma unroll
    for (int mt = 0; mt < MT; ++mt)
      af[mt] = *(const bf16x8*)(As + (a_row0 + mt * 32 + lr) * 32 + ki * 16 + lk);
    #pragma unroll
    for (int nt = 0; nt < NTT; ++nt)
      bf[nt] = *(const bf16x8*)(Bs + (b_row0 + nt * 32 + lr) * 32 + ki * 16 + lk);
    #pragma unroll
    for (int mt = 0; mt < MT; ++mt)
      #pragma unroll
      for (int nt = 0; nt < NTT; ++nt)
        acc[mt][nt] = __builtin_amdgcn_mfma_f32_32x32x16_bf16(af[mt], bf[nt], acc[mt][nt], 0, 0, 0);
  }
}

template<int AROWS, int BROWS, int NTHR, int MT, int NTT>
__device__ __forceinline__ void mainloop32(
    const unsigned short* __restrict__ A, long lda, long rowA,
    const unsigned short* __restrict__ Bt, long ldb, long rowB,
    int nsteps, unsigned short* AsBuf, unsigned short* BsBuf,
    int tid, int lane, int a_row0, int b_row0, f32x16 (&acc)[MT][NTT]) {
  constexpr int ASZ = AROWS * 32, BSZ = BROWS * 32;
  stage_tile32<AROWS, NTHR>(A, lda, rowA, 0, AsBuf, tid);
  stage_tile32<BROWS, NTHR>(Bt, ldb, rowB, 0, BsBuf, tid);
  __syncthreads();
  int cur = 0;
  for (int kt = 1; kt < nsteps; ++kt) {
    stage_tile32<AROWS, NTHR>(A, lda, rowA, kt * 32, AsBuf + (cur ^ 1) * ASZ, tid);
    stage_tile32<BROWS, NTHR>(Bt, ldb, rowB, kt * 32, BsBuf + (cur ^ 1) * BSZ, tid);
    compute_tile32<MT, NTT>(AsBuf + cur * ASZ, BsBuf + cur * BSZ, a_row0, b_row0, lane, acc);
    __syncthreads();
    cur ^= 1;
  }
  compute_tile32<MT, NTT>(AsBuf + cur * ASZ, BsBuf + cur * BSZ, a_row0, b_row0, lane, acc);
}

// ---- kernels ----

__global__ __launch_bounds__(256) void zero_out(float* __restrict__ out) {
  long i = (long)blockIdx.x * 256 + threadIdx.x;   // 1,048,576 f32x4
  ((f32x4*)out)[i] = (f32x4){0.f, 0.f, 0.f, 0.f};
}

__global__ __launch_bounds__(256) void convert_f32_bf16(const float* __restrict__ src,
                                                        unsigned short* __restrict__ dst) {
  long i = (long)blockIdx.x * 256 + threadIdx.x;  // 8 elems per thread
  f32x4 a = ((const f32x4*)src)[2 * i];
  f32x4 b = ((const f32x4*)src)[2 * i + 1];
  u16x8 o;
  #pragma unroll
  for (int j = 0; j < 4; ++j) { o[j] = f2bf(a[j]); o[4 + j] = f2bf(b[j]); }
  ((u16x8*)dst)[i] = o;
}

// wbT[n][k] = w_sel[k][n&511], n in [0,1536). Column reads hit L2/L3 (6 MB total).
__global__ __launch_bounds__(256) void build_wT(const float* __restrict__ wq,
                                                const float* __restrict__ wk,
                                                const float* __restrict__ wv,
                                                unsigned short* __restrict__ wbT) {
  int o = blockIdx.x * 256 + threadIdx.x;   // 1,572,864 total
  int n = o >> 10, k = o & 1023;
  const float* w = (n < 512) ? wq : ((n < 1024) ? wk : wv);
  int d = n & 511;
  wbT[o] = f2bf(w[(long)k * 512 + d]);
}

__global__ __launch_bounds__(256, 4) void qkv_gemm(
    const unsigned short* __restrict__ xb, const unsigned short* __restrict__ wbT,
    const float* __restrict__ bq, const float* __restrict__ bk, const float* __restrict__ bv,
    unsigned short* __restrict__ qb, unsigned short* __restrict__ kb,
    unsigned short* __restrict__ vb) {
  __shared__ unsigned short As[2][128 * 32], Bs[2][128 * 32];   // 32 KB
  int tid = threadIdx.x, wave = tid >> 6, lane = tid & 63;
  int wm = wave >> 1, wn = wave & 1;
  // XCD-aware bijective swizzle: 768 wgs, 96 per XCD chunk (768 % 8 == 0).
  int wg = blockIdx.x;
  int swz = (wg & 7) * 96 + (wg >> 3);
  int nb = swz % 12, mb = swz / 12;                // n fastest -> chunk shares A panel
  long rowA = (long)mb * 128, rowB = (long)nb * 128;
  f32x16 acc[2][2] = {};
  mainloop32<128, 128, 256, 2, 2>(xb, E_, rowA, wbT, E_, rowB, E_ / 32,
                                  &As[0][0], &Bs[0][0], tid, lane, wm * 64, wn * 64, acc);
  int lc = lane & 31, lhi = (lane >> 5) * 4;
  #pragma unroll
  for (int nt = 0; nt < 2; ++nt) {
    int n = (int)rowB + wn * 64 + nt * 32 + lc;
    int d = n & 511;
    float bias; unsigned short* dst;
    if (n < 512)       { bias = bq[d]; dst = qb; }
    else if (n < 1024) { bias = bk[d]; dst = kb; }
    else               { bias = bv[d]; dst = vb; }
    #pragma unroll
    for (int mt = 0; mt < 2; ++mt) {
      long mbase = rowA + wm * 64 + mt * 32 + lhi;
      #pragma unroll
      for (int r = 0; r < 16; ++r) {
        long m = mbase + (r & 3) + 8 * (r >> 2);
        dst[m * D_ + d] = f2bf(acc[mt][nt][r] + bias);
      }
    }
  }
}

__global__ __launch_bounds__(256) void transpose_v(const unsigned short* __restrict__ vb,
                                                   unsigned short* __restrict__ vtb) {
  int dblk = blockIdx.x;   // 0..7
  int sblk = blockIdx.y;   // 0..31
  int b = blockIdx.z;
  __shared__ unsigned short ls[64][72];  // pad 8 keeps 16B alignment, breaks conflicts
  int tid = threadIdx.x;
  int r = tid >> 3, c8 = (tid & 7) * 8;
  long d0 = (long)dblk * 64, s0 = (long)sblk * 64;
  #pragma unroll
  for (int p = 0; p < 2; ++p) {
    u16x8 v = *(const u16x8*)(vb + ((long)b * S_ + s0 + r + p * 32) * D_ + d0 + c8);
    *(u16x8*)&ls[r + p * 32][c8] = v;
  }
  __syncthreads();
  #pragma unroll
  for (int p = 0; p < 2; ++p) {
    int d = r + p * 32;
    u16x8 o;
    #pragma unroll
    for (int j = 0; j < 8; ++j) o[j] = ls[c8 + j][d];
    *(u16x8*)(vtb + ((long)b * D_ + d0 + d) * S_ + s0 + c8) = o;
  }
}

// 64-row score tiles: grid (jb=16, im=32, b=4); block (jb,im) computes
// scores[64*im .. +64)[128*jb .. +128); active iff 128*jb < 64*(im+1).
__global__ __launch_bounds__(256, 4) void scores_gemm(
    const unsigned short* __restrict__ qb, const unsigned short* __restrict__ kb,
    unsigned short* __restrict__ sc) {
  int jb = blockIdx.x, im = blockIdx.y, b = blockIdx.z;
  if (2 * jb > im) return;   // tile entirely above diagonal, never read downstream
  __shared__ unsigned short As[2][64 * 32], Bs[2][128 * 32];   // 24 KB
  int tid = threadIdx.x, wave = tid >> 6, lane = tid & 63;
  int wm = wave >> 1, wn = wave & 1;   // per-wave 32(m) x 64(n)
  const unsigned short* A  = qb + (long)b * S_ * D_;
  const unsigned short* Bt = kb + (long)b * S_ * D_;   // k stored [s][d] == [n][k]
  long rowA = (long)im * 64, rowB = (long)jb * 128;
  f32x16 acc[1][2] = {};
  mainloop32<64, 128, 256, 1, 2>(A, D_, rowA, Bt, D_, rowB, D_ / 32,
                                 &As[0][0], &Bs[0][0], tid, lane, wm * 32, wn * 64, acc);
  unsigned short* so = sc + (long)b * S_ * S_;
  int lc = lane & 31, lhi = (lane >> 5) * 4;
  long mbase = rowA + wm * 32 + lhi;
  #pragma unroll
  for (int nt = 0; nt < 2; ++nt) {
    long n = rowB + wn * 64 + nt * 32 + lc;
    #pragma unroll
    for (int r = 0; r < 16; ++r) {
      long m = mbase + (r & 3) + 8 * (r >> 2);
      so[m * S_ + n] = f2bf(acc[0][nt][r]);   // raw score; scale+mask in softmax
    }
  }
}

// one block per row; touches bf16 P only on cols [0, 64-aligned diag end);
// zeros above diag within that range -> PV K-loop (64-granular) reads exact data.
__global__ __launch_bounds__(256) void softmax_rows(unsigned short* __restrict__ sc) {
  int r = blockIdx.x, b = blockIdx.y;
  unsigned short* row = sc + ((long)b * S_ + r) * S_;
  int tid = threadIdx.x;
  int j0 = tid * 8;
  int limit = ((r >> 6) + 1) << 6;      // 64-aligned end of diagonal block
  bool act = (j0 < limit);
  u16x8 uv = {};
  if (act) uv = *(const u16x8*)(row + j0);
  float s[8];
  #pragma unroll
  for (int j = 0; j < 8; ++j) s[j] = (act && (j0 + j <= r)) ? bf2f(uv[j]) : -INFINITY;
  float mx = s[0];
  #pragma unroll
  for (int j = 1; j < 8; ++j) mx = fmaxf(mx, s[j]);
  #pragma unroll
  for (int o = 32; o > 0; o >>= 1) mx = fmaxf(mx, __shfl_xor(mx, o));
  __shared__ float red[4];
  int wave = tid >> 6, lane = tid & 63;
  if (lane == 0) red[wave] = mx;
  __syncthreads();
  mx = fmaxf(fmaxf(red[0], red[1]), fmaxf(red[2], red[3]));
  __syncthreads();
  const float c = 1.4426950408889634f / 22.627416997969522f;  // log2(e)/sqrt(512)
  float p[8]; float sum = 0.f;
  #pragma unroll
  for (int j = 0; j < 8; ++j) { p[j] = exp2f((s[j] - mx) * c); sum += p[j]; }
  #pragma unroll
  for (int o = 32; o > 0; o >>= 1) sum += __shfl_xor(sum, o);
  if (lane == 0) red[wave] = sum;
  __syncthreads();
  sum = red[0] + red[1] + red[2] + red[3];
  float inv = 1.f / sum;
  if (act) {
    u16x8 ov;
    #pragma unroll
    for (int j = 0; j < 8; ++j) ov[j] = f2bf(p[j] * inv);
    *(u16x8*)(row + j0) = ov;
  }
}

// split-K PV: grid (bn=4, bm*4+chunk=128, b=4). Each active block handles a
// 512-col K-chunk of the causal range for 64 output rows x 128 cols; single-
// chunk rows store, multi-chunk rows atomicAdd into pre-zeroed out.
__global__ __launch_bounds__(256, 4) void pv_gemm(
    const unsigned short* __restrict__ sc, const unsigned short* __restrict__ vtb,
    float* __restrict__ out) {
  int bn = blockIdx.x, zy = blockIdx.y, b = blockIdx.z;
  int bm = zy >> 2, ch = zy & 3;
  int kvEnd = 64 * (bm + 1);            // causal end for this 64-row block
  int k0 = ch * 512;
  if (k0 >= kvEnd) return;
  int k1 = min(k0 + 512, kvEnd);
  int nsteps = (k1 - k0) >> 5;          // 1..16 steps of BK=32
  __shared__ unsigned short As[2][64 * 32], Bs[2][128 * 32];   // 24 KB
  int tid = threadIdx.x, wave = tid >> 6, lane = tid & 63;
  int wm = wave >> 1, wn = wave & 1;   // per-wave 32(m) x 64(n)
  const unsigned short* A  = sc  + (long)b * S_ * S_ + k0;   // P, col-offset k0
  const unsigned short* Bt = vtb + (long)b * D_ * S_ + k0;   // V^T, col-offset k0
  long rowA = (long)bm * 64, rowB = (long)bn * 128;
  f32x16 acc[1][2] = {};
  mainloop32<64, 128, 256, 1, 2>(A, S_, rowA, Bt, S_, rowB, nsteps,
                                 &As[0][0], &Bs[0][0], tid, lane, wm * 32, wn * 64, acc);
  float* oo = out + (long)b * S_ * D_;
  int lc = lane & 31, lhi = (lane >> 5) * 4;
  long mbase = rowA + wm * 32 + lhi;
  bool single = (kvEnd <= 512);         // bm < 8: exactly one chunk covers it
  #pragma unroll
  for (int nt = 0; nt < 2; ++nt) {
    long n = rowB + wn * 64 + nt * 32 + lc;
    #pragma unroll
    for (int r = 0; r < 16; ++r) {
      long m = mbase + (r & 3) + 8 * (r >> 2);
      if (single) oo[m * D_ + n] = acc[0][nt][r];
      else        atomicAdd(&oo[m * D_ + n], acc[0][nt][r]);
    }
  }
}

extern "C" void kernel_launch(void* const* d_in, const int* in_sizes, int n_in,
                              void* d_out, int out_size, void* d_ws, size_t ws_size,
                              hipStream_t stream) {
  const float* x   = (const float*)d_in[0];
  const float* wq  = (const float*)d_in[1];
  const float* bq  = (const float*)d_in[2];
  const float* wk  = (const float*)d_in[3];
  const float* bk  = (const float*)d_in[4];
  const float* wv  = (const float*)d_in[5];
  const float* bv  = (const float*)d_in[6];
  float* out = (float*)d_out;

  // workspace layout (bytes), total 87,031,808 (~83 MB)
  char* ws = (char*)d_ws;
  unsigned short* xb  = (unsigned short*)(ws);                 // 16,777,216  x bf16 [8192][1024]
  unsigned short* wbT = (unsigned short*)(ws + 16777216);      //  3,145,728  w^T bf16 [1536][1024]
  unsigned short* qb  = (unsigned short*)(ws + 19922944);      //  8,388,608  q bf16 [8192][512]
  unsigned short* kb  = (unsigned short*)(ws + 28311552);      //  8,388,608
  unsigned short* vb  = (unsigned short*)(ws + 36700160);      //  8,388,608
  unsigned short* vtb = (unsigned short*)(ws + 45088768);      //  8,388,608  v^T bf16 [4][512][2048]
  unsigned short* sc  = (unsigned short*)(ws + 53477376);      // 33,554,432  scores/P bf16 [4][2048][2048]

  zero_out<<<dim3(4096), dim3(256), 0, stream>>>(out);
  convert_f32_bf16<<<dim3(4096), dim3(256), 0, stream>>>(x, xb);
  build_wT<<<dim3(6144), dim3(256), 0, stream>>>(wq, wk, wv, wbT);
  qkv_gemm<<<dim3(768), dim3(256), 0, stream>>>(xb, wbT, bq, bk, bv, qb, kb, vb);
  transpose_v<<<dim3(8, 32, 4), dim3(256), 0, stream>>>(vb, vtb);
  scores_gemm<<<dim3(16, 32, 4), dim3(256), 0, stream>>>(qb, kb, sc);
  softmax_rows<<<dim3(2048, 4), dim3(256), 0, stream>>>(sc);
  pv_gemm<<<dim3(4, 128, 4), dim3(256), 0, stream>>>(sc, vtb, out);
}

// Round 5
// 147.559 us; speedup vs baseline: 1.0596x; 1.0596x over previous
//
#include <hip/hip_runtime.h>
#include <math.h>

// Self-attention: B=4, S=2048, E=1024, D=512, fp32 in/out, bf16 MFMA internally.
// R5: LDS XOR-swizzle (16B granule, slot = g ^ ((row>>1)&3)) via pre-swizzled
//     global source + swizzled ds_read (linear global_load_lds dest). Kills the
//     16-way bank conflict of 64B-row tiles (R4 post-mortem: LDS pipe = 45us,
//     exactly pv's duration). Structure otherwise identical to R4.

typedef __attribute__((ext_vector_type(4))) float f32x4;
typedef __attribute__((ext_vector_type(16))) float f32x16;
typedef __attribute__((ext_vector_type(8))) short bf16x8;     // 8 bf16 = 4 VGPRs
typedef __attribute__((ext_vector_type(8))) unsigned short u16x8;

#define B_ 4
#define S_ 2048
#define E_ 1024
#define D_ 512

__device__ __forceinline__ unsigned short f2bf(float f) {
  unsigned u = __float_as_uint(f);
  u += 0x7fffu + ((u >> 16) & 1u);   // round-to-nearest-even
  return (unsigned short)(u >> 16);
}

__device__ __forceinline__ float bf2f(unsigned short h) {
  return __uint_as_float(((unsigned)h) << 16);
}

// ---- GEMM core: BK=32, 32x32x16 bf16 MFMA ----
// LDS tile ROWS x 32 bf16; logical 16B granule g of row r stored at slot
// g ^ ((r>>1)&3). Stage fetches global granule (slot ^ perm) into linear slot;
// reads XOR the same perm -> involution. 32-lane frag reads: 4-way conflict
// (was 16-way), m136: ~1.58x vs 5.7x.

template<int ROWS, int NTHR>
__device__ __forceinline__ void stage_tile32(const unsigned short* __restrict__ g, long ld,
                                             long rowBase, int kBase,
                                             unsigned short* lds, int tid) {
  constexpr int CALLS = (ROWS * 64) / (NTHR * 16);
  #pragma unroll
  for (int i = 0; i < CALLS; ++i) {
    int idx = i * NTHR + tid;
    int row = idx >> 2, cc = idx & 3;
    int src_g = cc ^ ((row >> 1) & 3);          // pre-swizzled global granule
    __builtin_amdgcn_global_load_lds(
      (const __attribute__((address_space(1))) void*)(g + (rowBase + row) * ld + kBase + src_g * 8),
      (__attribute__((address_space(3))) void*)(lds + idx * 8),
      16, 0, 0);
  }
}

// A frag for 32x32x16: lane reads A[row = lane&31][k = (lane>>5)*8 + 0..7].
template<int MT, int NTT>
__device__ __forceinline__ void compute_tile32(const unsigned short* As, const unsigned short* Bs,
                                               int a_row0, int b_row0, int lane,
                                               f32x16 (&acc)[MT][NTT]) {
  int lr = lane & 31, lhalf = lane >> 5;
  int p = (lr >> 1) & 3;                        // (row>>1)&3 with row0 % 32 == 0
  #pragma unroll
  for (int ki = 0; ki < 2; ++ki) {
    int slot = ((ki * 2 + lhalf) ^ p) * 8;      // swizzled granule offset (halfwords)
    bf16x8 af[MT], bf[NTT];
    #pragma unroll
    for (int mt = 0; mt < MT; ++mt)
      af[mt] = *(const bf16x8*)(As + (a_row0 + mt * 32 + lr) * 32 + slot);
    #pragma unroll
    for (int nt = 0; nt < NTT; ++nt)
      bf[nt] = *(const bf16x8*)(Bs + (b_row0 + nt * 32 + lr) * 32 + slot);
    #pragma unroll
    for (int mt = 0; mt < MT; ++mt)
      #pragma unroll
      for (int nt = 0; nt < NTT; ++nt)
        acc[mt][nt] = __builtin_amdgcn_mfma_f32_32x32x16_bf16(af[mt], bf[nt], acc[mt][nt], 0, 0, 0);
  }
}

template<int AROWS, int BROWS, int NTHR, int MT, int NTT>
__device__ __forceinline__ void mainloop32(
    const unsigned short* __restrict__ A, long lda, long rowA,
    const unsigned short* __restrict__ Bt, long ldb, long rowB,
    int nsteps, unsigned short* AsBuf, unsigned short* BsBuf,
    int tid, int lane, int a_row0, int b_row0, f32x16 (&acc)[MT][NTT]) {
  constexpr int ASZ = AROWS * 32, BSZ = BROWS * 32;
  stage_tile32<AROWS, NTHR>(A, lda, rowA, 0, AsBuf, tid);
  stage_tile32<BROWS, NTHR>(Bt, ldb, rowB, 0, BsBuf, tid);
  __syncthreads();
  int cur = 0;
  for (int kt = 1; kt < nsteps; ++kt) {
    stage_tile32<AROWS, NTHR>(A, lda, rowA, kt * 32, AsBuf + (cur ^ 1) * ASZ, tid);
    stage_tile32<BROWS, NTHR>(Bt, ldb, rowB, kt * 32, BsBuf + (cur ^ 1) * BSZ, tid);
    compute_tile32<MT, NTT>(AsBuf + cur * ASZ, BsBuf + cur * BSZ, a_row0, b_row0, lane, acc);
    __syncthreads();
    cur ^= 1;
  }
  compute_tile32<MT, NTT>(AsBuf + cur * ASZ, BsBuf + cur * BSZ, a_row0, b_row0, lane, acc);
}

// ---- kernels ----

__global__ __launch_bounds__(256) void zero_out(float* __restrict__ out) {
  long i = (long)blockIdx.x * 256 + threadIdx.x;   // 1,048,576 f32x4
  ((f32x4*)out)[i] = (f32x4){0.f, 0.f, 0.f, 0.f};
}

__global__ __launch_bounds__(256) void convert_f32_bf16(const float* __restrict__ src,
                                                        unsigned short* __restrict__ dst) {
  long i = (long)blockIdx.x * 256 + threadIdx.x;  // 8 elems per thread
  f32x4 a = ((const f32x4*)src)[2 * i];
  f32x4 b = ((const f32x4*)src)[2 * i + 1];
  u16x8 o;
  #pragma unroll
  for (int j = 0; j < 4; ++j) { o[j] = f2bf(a[j]); o[4 + j] = f2bf(b[j]); }
  ((u16x8*)dst)[i] = o;
}

// wbT[n][k] = w_sel[k][n&511], n in [0,1536). Column reads hit L2/L3 (6 MB total).
__global__ __launch_bounds__(256) void build_wT(const float* __restrict__ wq,
                                                const float* __restrict__ wk,
                                                const float* __restrict__ wv,
                                                unsigned short* __restrict__ wbT) {
  int o = blockIdx.x * 256 + threadIdx.x;   // 1,572,864 total
  int n = o >> 10, k = o & 1023;
  const float* w = (n < 512) ? wq : ((n < 1024) ? wk : wv);
  int d = n & 511;
  wbT[o] = f2bf(w[(long)k * 512 + d]);
}

__global__ __launch_bounds__(256, 4) void qkv_gemm(
    const unsigned short* __restrict__ xb, const unsigned short* __restrict__ wbT,
    const float* __restrict__ bq, const float* __restrict__ bk, const float* __restrict__ bv,
    unsigned short* __restrict__ qb, unsigned short* __restrict__ kb,
    unsigned short* __restrict__ vb) {
  __shared__ unsigned short As[2][128 * 32], Bs[2][128 * 32];   // 32 KB
  int tid = threadIdx.x, wave = tid >> 6, lane = tid & 63;
  int wm = wave >> 1, wn = wave & 1;
  // XCD-aware bijective swizzle: 768 wgs, 96 per XCD chunk (768 % 8 == 0).
  int wg = blockIdx.x;
  int swz = (wg & 7) * 96 + (wg >> 3);
  int nb = swz % 12, mb = swz / 12;                // n fastest -> chunk shares A panel
  long rowA = (long)mb * 128, rowB = (long)nb * 128;
  f32x16 acc[2][2] = {};
  mainloop32<128, 128, 256, 2, 2>(xb, E_, rowA, wbT, E_, rowB, E_ / 32,
                                  &As[0][0], &Bs[0][0], tid, lane, wm * 64, wn * 64, acc);
  int lc = lane & 31, lhi = (lane >> 5) * 4;
  #pragma unroll
  for (int nt = 0; nt < 2; ++nt) {
    int n = (int)rowB + wn * 64 + nt * 32 + lc;
    int d = n & 511;
    float bias; unsigned short* dst;
    if (n < 512)       { bias = bq[d]; dst = qb; }
    else if (n < 1024) { bias = bk[d]; dst = kb; }
    else               { bias = bv[d]; dst = vb; }
    #pragma unroll
    for (int mt = 0; mt < 2; ++mt) {
      long mbase = rowA + wm * 64 + mt * 32 + lhi;
      #pragma unroll
      for (int r = 0; r < 16; ++r) {
        long m = mbase + (r & 3) + 8 * (r >> 2);
        dst[m * D_ + d] = f2bf(acc[mt][nt][r] + bias);
      }
    }
  }
}

__global__ __launch_bounds__(256) void transpose_v(const unsigned short* __restrict__ vb,
                                                   unsigned short* __restrict__ vtb) {
  int dblk = blockIdx.x;   // 0..7
  int sblk = blockIdx.y;   // 0..31
  int b = blockIdx.z;
  __shared__ unsigned short ls[64][72];  // pad 8 keeps 16B alignment, breaks conflicts
  int tid = threadIdx.x;
  int r = tid >> 3, c8 = (tid & 7) * 8;
  long d0 = (long)dblk * 64, s0 = (long)sblk * 64;
  #pragma unroll
  for (int p = 0; p < 2; ++p) {
    u16x8 v = *(const u16x8*)(vb + ((long)b * S_ + s0 + r + p * 32) * D_ + d0 + c8);
    *(u16x8*)&ls[r + p * 32][c8] = v;
  }
  __syncthreads();
  #pragma unroll
  for (int p = 0; p < 2; ++p) {
    int d = r + p * 32;
    u16x8 o;
    #pragma unroll
    for (int j = 0; j < 8; ++j) o[j] = ls[c8 + j][d];
    *(u16x8*)(vtb + ((long)b * D_ + d0 + d) * S_ + s0 + c8) = o;
  }
}

// 64-row score tiles: grid (jb=16, im=32, b=4); block (jb,im) computes
// scores[64*im .. +64)[128*jb .. +128); active iff 128*jb < 64*(im+1).
__global__ __launch_bounds__(256, 4) void scores_gemm(
    const unsigned short* __restrict__ qb, const unsigned short* __restrict__ kb,
    unsigned short* __restrict__ sc) {
  int jb = blockIdx.x, im = blockIdx.y, b = blockIdx.z;
  if (2 * jb > im) return;   // tile entirely above diagonal, never read downstream
  __shared__ unsigned short As[2][64 * 32], Bs[2][128 * 32];   // 24 KB
  int tid = threadIdx.x, wave = tid >> 6, lane = tid & 63;
  int wm = wave >> 1, wn = wave & 1;   // per-wave 32(m) x 64(n)
  const unsigned short* A  = qb + (long)b * S_ * D_;
  const unsigned short* Bt = kb + (long)b * S_ * D_;   // k stored [s][d] == [n][k]
  long rowA = (long)im * 64, rowB = (long)jb * 128;
  f32x16 acc[1][2] = {};
  mainloop32<64, 128, 256, 1, 2>(A, D_, rowA, Bt, D_, rowB, D_ / 32,
                                 &As[0][0], &Bs[0][0], tid, lane, wm * 32, wn * 64, acc);
  unsigned short* so = sc + (long)b * S_ * S_;
  int lc = lane & 31, lhi = (lane >> 5) * 4;
  long mbase = rowA + wm * 32 + lhi;
  #pragma unroll
  for (int nt = 0; nt < 2; ++nt) {
    long n = rowB + wn * 64 + nt * 32 + lc;
    #pragma unroll
    for (int r = 0; r < 16; ++r) {
      long m = mbase + (r & 3) + 8 * (r >> 2);
      so[m * S_ + n] = f2bf(acc[0][nt][r]);   // raw score; scale+mask in softmax
    }
  }
}

// one block per row; touches bf16 P only on cols [0, 64-aligned diag end);
// zeros above diag within that range -> PV K-loop (64-granular) reads exact data.
__global__ __launch_bounds__(256) void softmax_rows(unsigned short* __restrict__ sc) {
  int r = blockIdx.x, b = blockIdx.y;
  unsigned short* row = sc + ((long)b * S_ + r) * S_;
  int tid = threadIdx.x;
  int j0 = tid * 8;
  int limit = ((r >> 6) + 1) << 6;      // 64-aligned end of diagonal block
  bool act = (j0 < limit);
  u16x8 uv = {};
  if (act) uv = *(const u16x8*)(row + j0);
  float s[8];
  #pragma unroll
  for (int j = 0; j < 8; ++j) s[j] = (act && (j0 + j <= r)) ? bf2f(uv[j]) : -INFINITY;
  float mx = s[0];
  #pragma unroll
  for (int j = 1; j < 8; ++j) mx = fmaxf(mx, s[j]);
  #pragma unroll
  for (int o = 32; o > 0; o >>= 1) mx = fmaxf(mx, __shfl_xor(mx, o));
  __shared__ float red[4];
  int wave = tid >> 6, lane = tid & 63;
  if (lane == 0) red[wave] = mx;
  __syncthreads();
  mx = fmaxf(fmaxf(red[0], red[1]), fmaxf(red[2], red[3]));
  __syncthreads();
  const float c = 1.4426950408889634f / 22.627416997969522f;  // log2(e)/sqrt(512)
  float p[8]; float sum = 0.f;
  #pragma unroll
  for (int j = 0; j < 8; ++j) { p[j] = exp2f((s[j] - mx) * c); sum += p[j]; }
  #pragma unroll
  for (int o = 32; o > 0; o >>= 1) sum += __shfl_xor(sum, o);
  if (lane == 0) red[wave] = sum;
  __syncthreads();
  sum = red[0] + red[1] + red[2] + red[3];
  float inv = 1.f / sum;
  if (act) {
    u16x8 ov;
    #pragma unroll
    for (int j = 0; j < 8; ++j) ov[j] = f2bf(p[j] * inv);
    *(u16x8*)(row + j0) = ov;
  }
}

// split-K PV: grid (bn=4, bm*4+chunk=128, b=4). Each active block handles a
// 512-col K-chunk of the causal range for 64 output rows x 128 cols; single-
// chunk rows store, multi-chunk rows atomicAdd into pre-zeroed out.
__global__ __launch_bounds__(256, 4) void pv_gemm(
    const unsigned short* __restrict__ sc, const unsigned short* __restrict__ vtb,
    float* __restrict__ out) {
  int bn = blockIdx.x, zy = blockIdx.y, b = blockIdx.z;
  int bm = zy >> 2, ch = zy & 3;
  int kvEnd = 64 * (bm + 1);            // causal end for this 64-row block
  int k0 = ch * 512;
  if (k0 >= kvEnd) return;
  int k1 = min(k0 + 512, kvEnd);
  int nsteps = (k1 - k0) >> 5;          // 1..16 steps of BK=32
  __shared__ unsigned short As[2][64 * 32], Bs[2][128 * 32];   // 24 KB
  int tid = threadIdx.x, wave = tid >> 6, lane = tid & 63;
  int wm = wave >> 1, wn = wave & 1;   // per-wave 32(m) x 64(n)
  const unsigned short* A  = sc  + (long)b * S_ * S_ + k0;   // P, col-offset k0
  const unsigned short* Bt = vtb + (long)b * D_ * S_ + k0;   // V^T, col-offset k0
  long rowA = (long)bm * 64, rowB = (long)bn * 128;
  f32x16 acc[1][2] = {};
  mainloop32<64, 128, 256, 1, 2>(A, S_, rowA, Bt, S_, rowB, nsteps,
                                 &As[0][0], &Bs[0][0], tid, lane, wm * 32, wn * 64, acc);
  float* oo = out + (long)b * S_ * D_;
  int lc = lane & 31, lhi = (lane >> 5) * 4;
  long mbase = rowA + wm * 32 + lhi;
  bool single = (kvEnd <= 512);         // bm < 8: exactly one chunk covers it
  #pragma unroll
  for (int nt = 0; nt < 2; ++nt) {
    long n = rowB + wn * 64 + nt * 32 + lc;
    #pragma unroll
    for (int r = 0; r < 16; ++r) {
      long m = mbase + (r & 3) + 8 * (r >> 2);
      if (single) oo[m * D_ + n] = acc[0][nt][r];
      else        atomicAdd(&oo[m * D_ + n], acc[0][nt][r]);
    }
  }
}

extern "C" void kernel_launch(void* const* d_in, const int* in_sizes, int n_in,
                              void* d_out, int out_size, void* d_ws, size_t ws_size,
                              hipStream_t stream) {
  const float* x   = (const float*)d_in[0];
  const float* wq  = (const float*)d_in[1];
  const float* bq  = (const float*)d_in[2];
  const float* wk  = (const float*)d_in[3];
  const float* bk  = (const float*)d_in[4];
  const float* wv  = (const float*)d_in[5];
  const float* bv  = (const float*)d_in[6];
  float* out = (float*)d_out;

  // workspace layout (bytes), total 87,031,808 (~83 MB)
  char* ws = (char*)d_ws;
  unsigned short* xb  = (unsigned short*)(ws);                 // 16,777,216  x bf16 [8192][1024]
  unsigned short* wbT = (unsigned short*)(ws + 16777216);      //  3,145,728  w^T bf16 [1536][1024]
  unsigned short* qb  = (unsigned short*)(ws + 19922944);      //  8,388,608  q bf16 [8192][512]
  unsigned short* kb  = (unsigned short*)(ws + 28311552);      //  8,388,608
  unsigned short* vb  = (unsigned short*)(ws + 36700160);      //  8,388,608
  unsigned short* vtb = (unsigned short*)(ws + 45088768);      //  8,388,608  v^T bf16 [4][512][2048]
  unsigned short* sc  = (unsigned short*)(ws + 53477376);      // 33,554,432  scores/P bf16 [4][2048][2048]

  zero_out<<<dim3(4096), dim3(256), 0, stream>>>(out);
  convert_f32_bf16<<<dim3(4096), dim3(256), 0, stream>>>(x, xb);
  build_wT<<<dim3(6144), dim3(256), 0, stream>>>(wq, wk, wv, wbT);
  qkv_gemm<<<dim3(768), dim3(256), 0, stream>>>(xb, wbT, bq, bk, bv, qb, kb, vb);
  transpose_v<<<dim3(8, 32, 4), dim3(256), 0, stream>>>(vb, vtb);
  scores_gemm<<<dim3(16, 32, 4), dim3(256), 0, stream>>>(qb, kb, sc);
  softmax_rows<<<dim3(2048, 4), dim3(256), 0, stream>>>(sc);
  pv_gemm<<<dim3(4, 128, 4), dim3(256), 0, stream>>>(sc, vtb, out);
}

// Round 6
// 145.357 us; speedup vs baseline: 1.0756x; 1.0151x over previous
//
#include <hip/hip_runtime.h>
#include <math.h>

// Self-attention: B=4, S=2048, E=1024, D=512, fp32 in/out, bf16 MFMA internally.
// R6: counted-vmcnt 3-buffer single-barrier pipeline in the GEMM mainloop
//     (T3/T4: loads for 2 steps ahead stay in flight across s_barrier; never
//     drain vmcnt to 0 in-loop). R4/R5 post-mortem: 2-phase __syncthreads
//     drained vmcnt each step -> ~8 B/cy/CU ingest, latency-bound.
//     Longest blocks dispatched first (reversed bm/im).

typedef __attribute__((ext_vector_type(4))) float f32x4;
typedef __attribute__((ext_vector_type(16))) float f32x16;
typedef __attribute__((ext_vector_type(8))) short bf16x8;     // 8 bf16 = 4 VGPRs
typedef __attribute__((ext_vector_type(8))) unsigned short u16x8;

#define B_ 4
#define S_ 2048
#define E_ 1024
#define D_ 512

__device__ __forceinline__ unsigned short f2bf(float f) {
  unsigned u = __float_as_uint(f);
  u += 0x7fffu + ((u >> 16) & 1u);   // round-to-nearest-even
  return (unsigned short)(u >> 16);
}

__device__ __forceinline__ float bf2f(unsigned short h) {
  return __uint_as_float(((unsigned)h) << 16);
}

template<int N> __device__ __forceinline__ void wait_vm() {
  if constexpr (N == 0)      asm volatile("s_waitcnt vmcnt(0)" ::: "memory");
  else if constexpr (N == 3) asm volatile("s_waitcnt vmcnt(3)" ::: "memory");
  else if constexpr (N == 4) asm volatile("s_waitcnt vmcnt(4)" ::: "memory");
  else static_assert(N != N, "unsupported vmcnt");
}

// ---- GEMM core: BK=32, 32x32x16 bf16 MFMA ----
// LDS tile ROWS x 32 bf16; 16B granule g of row r stored at slot g ^ ((r>>1)&3)
// (R5 swizzle: 16-way -> 4-way bank conflict). Stage pre-swizzles the GLOBAL
// source granule; LDS dest stays linear (global_load_lds constraint).

template<int ROWS, int NTHR>
__device__ __forceinline__ void stage_tile32(const unsigned short* __restrict__ g, long ld,
                                             long rowBase, int kBase,
                                             unsigned short* lds, int tid) {
  constexpr int CALLS = (ROWS * 64) / (NTHR * 16);
  #pragma unroll
  for (int i = 0; i < CALLS; ++i) {
    int idx = i * NTHR + tid;
    int row = idx >> 2, cc = idx & 3;
    int src_g = cc ^ ((row >> 1) & 3);          // pre-swizzled global granule
    __builtin_amdgcn_global_load_lds(
      (const __attribute__((address_space(1))) void*)(g + (rowBase + row) * ld + kBase + src_g * 8),
      (__attribute__((address_space(3))) void*)(lds + idx * 8),
      16, 0, 0);
  }
}

// A frag for 32x32x16: lane reads A[row = lane&31][k = (lane>>5)*8 + 0..7].
template<int MT, int NTT>
__device__ __forceinline__ void compute_tile32(const unsigned short* As, const unsigned short* Bs,
                                               int a_row0, int b_row0, int lane,
                                               f32x16 (&acc)[MT][NTT]) {
  int lr = lane & 31, lhalf = lane >> 5;
  int p = (lr >> 1) & 3;                        // (row>>1)&3 with row0 % 32 == 0
  #pragma unroll
  for (int ki = 0; ki < 2; ++ki) {
    int slot = ((ki * 2 + lhalf) ^ p) * 8;      // swizzled granule offset (halfwords)
    bf16x8 af[MT], bf[NTT];
    #pragma unroll
    for (int mt = 0; mt < MT; ++mt)
      af[mt] = *(const bf16x8*)(As + (a_row0 + mt * 32 + lr) * 32 + slot);
    #pragma unroll
    for (int nt = 0; nt < NTT; ++nt)
      bf[nt] = *(const bf16x8*)(Bs + (b_row0 + nt * 32 + lr) * 32 + slot);
    #pragma unroll
    for (int mt = 0; mt < MT; ++mt)
      #pragma unroll
      for (int nt = 0; nt < NTT; ++nt)
        acc[mt][nt] = __builtin_amdgcn_mfma_f32_32x32x16_bf16(af[mt], bf[nt], acc[mt][nt], 0, 0, 0);
  }
}

// 3-buffer pipeline, one barrier per K-step, counted vmcnt (never 0 in-loop).
// Iter t: {wait own loads of step t (vmcnt<=LPS); barrier; compute(t);
//          stage(t+2)}. Buffer t+2 == buffer t-1: safe, all waves passed this
//          iter's barrier only after finishing compute(t-1).
template<int AROWS, int BROWS, int NTHR, int MT, int NTT>
__device__ __forceinline__ void mainloop32(
    const unsigned short* __restrict__ A, long lda, long rowA,
    const unsigned short* __restrict__ Bt, long ldb, long rowB,
    int nsteps, unsigned short* AsBuf, unsigned short* BsBuf,
    int tid, int lane, int a_row0, int b_row0, f32x16 (&acc)[MT][NTT]) {
  constexpr int ASZ = AROWS * 32, BSZ = BROWS * 32;
  constexpr int LPS = (AROWS * 64) / (NTHR * 16) + (BROWS * 64) / (NTHR * 16);
  unsigned short *a0 = AsBuf, *a1 = AsBuf + ASZ, *a2 = AsBuf + 2 * ASZ;
  unsigned short *b0 = BsBuf, *b1 = BsBuf + BSZ, *b2 = BsBuf + 2 * BSZ;
  stage_tile32<AROWS, NTHR>(A, lda, rowA, 0, a0, tid);
  stage_tile32<BROWS, NTHR>(Bt, ldb, rowB, 0, b0, tid);
  if (nsteps > 1) {
    stage_tile32<AROWS, NTHR>(A, lda, rowA, 32, a1, tid);
    stage_tile32<BROWS, NTHR>(Bt, ldb, rowB, 32, b1, tid);
  }
  for (int t = 0; t < nsteps; ++t) {
    if (t < nsteps - 1) wait_vm<LPS>(); else wait_vm<0>();
    __builtin_amdgcn_s_barrier();
    __builtin_amdgcn_sched_barrier(0);
    compute_tile32<MT, NTT>(a0, b0, a_row0, b_row0, lane, acc);
    if (t + 2 < nsteps) {
      stage_tile32<AROWS, NTHR>(A, lda, rowA, (t + 2) * 32, a2, tid);
      stage_tile32<BROWS, NTHR>(Bt, ldb, rowB, (t + 2) * 32, b2, tid);
    }
    unsigned short* ta = a0; a0 = a1; a1 = a2; a2 = ta;
    unsigned short* tb = b0; b0 = b1; b1 = b2; b2 = tb;
  }
}

// ---- kernels ----

__global__ __launch_bounds__(256) void zero_out(float* __restrict__ out) {
  long i = (long)blockIdx.x * 256 + threadIdx.x;   // 1,048,576 f32x4
  ((f32x4*)out)[i] = (f32x4){0.f, 0.f, 0.f, 0.f};
}

__global__ __launch_bounds__(256) void convert_f32_bf16(const float* __restrict__ src,
                                                        unsigned short* __restrict__ dst) {
  long i = (long)blockIdx.x * 256 + threadIdx.x;  // 8 elems per thread
  f32x4 a = ((const f32x4*)src)[2 * i];
  f32x4 b = ((const f32x4*)src)[2 * i + 1];
  u16x8 o;
  #pragma unroll
  for (int j = 0; j < 4; ++j) { o[j] = f2bf(a[j]); o[4 + j] = f2bf(b[j]); }
  ((u16x8*)dst)[i] = o;
}

// wbT[n][k] = w_sel[k][n&511], n in [0,1536). Column reads hit L2/L3 (6 MB total).
__global__ __launch_bounds__(256) void build_wT(const float* __restrict__ wq,
                                                const float* __restrict__ wk,
                                                const float* __restrict__ wv,
                                                unsigned short* __restrict__ wbT) {
  int o = blockIdx.x * 256 + threadIdx.x;   // 1,572,864 total
  int n = o >> 10, k = o & 1023;
  const float* w = (n < 512) ? wq : ((n < 1024) ? wk : wv);
  int d = n & 511;
  wbT[o] = f2bf(w[(long)k * 512 + d]);
}

__global__ __launch_bounds__(256, 3) void qkv_gemm(
    const unsigned short* __restrict__ xb, const unsigned short* __restrict__ wbT,
    const float* __restrict__ bq, const float* __restrict__ bk, const float* __restrict__ bv,
    unsigned short* __restrict__ qb, unsigned short* __restrict__ kb,
    unsigned short* __restrict__ vb) {
  __shared__ unsigned short As[3][128 * 32], Bs[3][128 * 32];   // 48 KB
  int tid = threadIdx.x, wave = tid >> 6, lane = tid & 63;
  int wm = wave >> 1, wn = wave & 1;
  // XCD-aware bijective swizzle: 768 wgs, 96 per XCD chunk (768 % 8 == 0).
  int wg = blockIdx.x;
  int swz = (wg & 7) * 96 + (wg >> 3);
  int nb = swz % 12, mb = swz / 12;                // n fastest -> chunk shares A panel
  long rowA = (long)mb * 128, rowB = (long)nb * 128;
  f32x16 acc[2][2] = {};
  mainloop32<128, 128, 256, 2, 2>(xb, E_, rowA, wbT, E_, rowB, E_ / 32,
                                  &As[0][0], &Bs[0][0], tid, lane, wm * 64, wn * 64, acc);
  int lc = lane & 31, lhi = (lane >> 5) * 4;
  #pragma unroll
  for (int nt = 0; nt < 2; ++nt) {
    int n = (int)rowB + wn * 64 + nt * 32 + lc;
    int d = n & 511;
    float bias; unsigned short* dst;
    if (n < 512)       { bias = bq[d]; dst = qb; }
    else if (n < 1024) { bias = bk[d]; dst = kb; }
    else               { bias = bv[d]; dst = vb; }
    #pragma unroll
    for (int mt = 0; mt < 2; ++mt) {
      long mbase = rowA + wm * 64 + mt * 32 + lhi;
      #pragma unroll
      for (int r = 0; r < 16; ++r) {
        long m = mbase + (r & 3) + 8 * (r >> 2);
        dst[m * D_ + d] = f2bf(acc[mt][nt][r] + bias);
      }
    }
  }
}

__global__ __launch_bounds__(256) void transpose_v(const unsigned short* __restrict__ vb,
                                                   unsigned short* __restrict__ vtb) {
  int dblk = blockIdx.x;   // 0..7
  int sblk = blockIdx.y;   // 0..31
  int b = blockIdx.z;
  __shared__ unsigned short ls[64][72];  // pad 8 keeps 16B alignment, breaks conflicts
  int tid = threadIdx.x;
  int r = tid >> 3, c8 = (tid & 7) * 8;
  long d0 = (long)dblk * 64, s0 = (long)sblk * 64;
  #pragma unroll
  for (int p = 0; p < 2; ++p) {
    u16x8 v = *(const u16x8*)(vb + ((long)b * S_ + s0 + r + p * 32) * D_ + d0 + c8);
    *(u16x8*)&ls[r + p * 32][c8] = v;
  }
  __syncthreads();
  #pragma unroll
  for (int p = 0; p < 2; ++p) {
    int d = r + p * 32;
    u16x8 o;
    #pragma unroll
    for (int j = 0; j < 8; ++j) o[j] = ls[c8 + j][d];
    *(u16x8*)(vtb + ((long)b * D_ + d0 + d) * S_ + s0 + c8) = o;
  }
}

// 64-row score tiles: grid (jb=16, 32, b=4); im reversed so longest first.
__global__ __launch_bounds__(256, 4) void scores_gemm(
    const unsigned short* __restrict__ qb, const unsigned short* __restrict__ kb,
    unsigned short* __restrict__ sc) {
  int jb = blockIdx.x, im = 31 - blockIdx.y, b = blockIdx.z;
  if (2 * jb > im) return;   // tile entirely above diagonal, never read downstream
  __shared__ unsigned short As[3][64 * 32], Bs[3][128 * 32];   // 36 KB
  int tid = threadIdx.x, wave = tid >> 6, lane = tid & 63;
  int wm = wave >> 1, wn = wave & 1;   // per-wave 32(m) x 64(n)
  const unsigned short* A  = qb + (long)b * S_ * D_;
  const unsigned short* Bt = kb + (long)b * S_ * D_;   // k stored [s][d] == [n][k]
  long rowA = (long)im * 64, rowB = (long)jb * 128;
  f32x16 acc[1][2] = {};
  mainloop32<64, 128, 256, 1, 2>(A, D_, rowA, Bt, D_, rowB, D_ / 32,
                                 &As[0][0], &Bs[0][0], tid, lane, wm * 32, wn * 64, acc);
  unsigned short* so = sc + (long)b * S_ * S_;
  int lc = lane & 31, lhi = (lane >> 5) * 4;
  long mbase = rowA + wm * 32 + lhi;
  #pragma unroll
  for (int nt = 0; nt < 2; ++nt) {
    long n = rowB + wn * 64 + nt * 32 + lc;
    #pragma unroll
    for (int r = 0; r < 16; ++r) {
      long m = mbase + (r & 3) + 8 * (r >> 2);
      so[m * S_ + n] = f2bf(acc[0][nt][r]);   // raw score; scale+mask in softmax
    }
  }
}

// one block per row; touches bf16 P only on cols [0, 64-aligned diag end);
// zeros above diag within that range -> PV K-loop (64-granular) reads exact data.
__global__ __launch_bounds__(256) void softmax_rows(unsigned short* __restrict__ sc) {
  int r = blockIdx.x, b = blockIdx.y;
  unsigned short* row = sc + ((long)b * S_ + r) * S_;
  int tid = threadIdx.x;
  int j0 = tid * 8;
  int limit = ((r >> 6) + 1) << 6;      // 64-aligned end of diagonal block
  bool act = (j0 < limit);
  u16x8 uv = {};
  if (act) uv = *(const u16x8*)(row + j0);
  float s[8];
  #pragma unroll
  for (int j = 0; j < 8; ++j) s[j] = (act && (j0 + j <= r)) ? bf2f(uv[j]) : -INFINITY;
  float mx = s[0];
  #pragma unroll
  for (int j = 1; j < 8; ++j) mx = fmaxf(mx, s[j]);
  #pragma unroll
  for (int o = 32; o > 0; o >>= 1) mx = fmaxf(mx, __shfl_xor(mx, o));
  __shared__ float red[4];
  int wave = tid >> 6, lane = tid & 63;
  if (lane == 0) red[wave] = mx;
  __syncthreads();
  mx = fmaxf(fmaxf(red[0], red[1]), fmaxf(red[2], red[3]));
  __syncthreads();
  const float c = 1.4426950408889634f / 22.627416997969522f;  // log2(e)/sqrt(512)
  float p[8]; float sum = 0.f;
  #pragma unroll
  for (int j = 0; j < 8; ++j) { p[j] = exp2f((s[j] - mx) * c); sum += p[j]; }
  #pragma unroll
  for (int o = 32; o > 0; o >>= 1) sum += __shfl_xor(sum, o);
  if (lane == 0) red[wave] = sum;
  __syncthreads();
  sum = red[0] + red[1] + red[2] + red[3];
  float inv = 1.f / sum;
  if (act) {
    u16x8 ov;
    #pragma unroll
    for (int j = 0; j < 8; ++j) ov[j] = f2bf(p[j] * inv);
    *(u16x8*)(row + j0) = ov;
  }
}

// split-K PV: grid (bn=4, 128, b=4); y encodes (bm reversed, chunk) so the
// longest blocks dispatch first. 512-col K-chunks; single-chunk rows store,
// multi-chunk rows atomicAdd into pre-zeroed out.
__global__ __launch_bounds__(256, 4) void pv_gemm(
    const unsigned short* __restrict__ sc, const unsigned short* __restrict__ vtb,
    float* __restrict__ out) {
  int bn = blockIdx.x, zy = blockIdx.y, b = blockIdx.z;
  int bm = 31 - (zy >> 2), ch = zy & 3;
  int kvEnd = 64 * (bm + 1);            // causal end for this 64-row block
  int k0 = ch * 512;
  if (k0 >= kvEnd) return;
  int k1 = min(k0 + 512, kvEnd);
  int nsteps = (k1 - k0) >> 5;          // 1..16 steps of BK=32
  __shared__ unsigned short As[3][64 * 32], Bs[3][128 * 32];   // 36 KB
  int tid = threadIdx.x, wave = tid >> 6, lane = tid & 63;
  int wm = wave >> 1, wn = wave & 1;   // per-wave 32(m) x 64(n)
  const unsigned short* A  = sc  + (long)b * S_ * S_ + k0;   // P, col-offset k0
  const unsigned short* Bt = vtb + (long)b * D_ * S_ + k0;   // V^T, col-offset k0
  long rowA = (long)bm * 64, rowB = (long)bn * 128;
  f32x16 acc[1][2] = {};
  mainloop32<64, 128, 256, 1, 2>(A, S_, rowA, Bt, S_, rowB, nsteps,
                                 &As[0][0], &Bs[0][0], tid, lane, wm * 32, wn * 64, acc);
  float* oo = out + (long)b * S_ * D_;
  int lc = lane & 31, lhi = (lane >> 5) * 4;
  long mbase = rowA + wm * 32 + lhi;
  bool single = (kvEnd <= 512);         // bm < 8: exactly one chunk covers it
  #pragma unroll
  for (int nt = 0; nt < 2; ++nt) {
    long n = rowB + wn * 64 + nt * 32 + lc;
    #pragma unroll
    for (int r = 0; r < 16; ++r) {
      long m = mbase + (r & 3) + 8 * (r >> 2);
      if (single) oo[m * D_ + n] = acc[0][nt][r];
      else        atomicAdd(&oo[m * D_ + n], acc[0][nt][r]);
    }
  }
}

extern "C" void kernel_launch(void* const* d_in, const int* in_sizes, int n_in,
                              void* d_out, int out_size, void* d_ws, size_t ws_size,
                              hipStream_t stream) {
  const float* x   = (const float*)d_in[0];
  const float* wq  = (const float*)d_in[1];
  const float* bq  = (const float*)d_in[2];
  const float* wk  = (const float*)d_in[3];
  const float* bk  = (const float*)d_in[4];
  const float* wv  = (const float*)d_in[5];
  const float* bv  = (const float*)d_in[6];
  float* out = (float*)d_out;

  // workspace layout (bytes), total 87,031,808 (~83 MB)
  char* ws = (char*)d_ws;
  unsigned short* xb  = (unsigned short*)(ws);                 // 16,777,216  x bf16 [8192][1024]
  unsigned short* wbT = (unsigned short*)(ws + 16777216);      //  3,145,728  w^T bf16 [1536][1024]
  unsigned short* qb  = (unsigned short*)(ws + 19922944);      //  8,388,608  q bf16 [8192][512]
  unsigned short* kb  = (unsigned short*)(ws + 28311552);      //  8,388,608
  unsigned short* vb  = (unsigned short*)(ws + 36700160);      //  8,388,608
  unsigned short* vtb = (unsigned short*)(ws + 45088768);      //  8,388,608  v^T bf16 [4][512][2048]
  unsigned short* sc  = (unsigned short*)(ws + 53477376);      // 33,554,432  scores/P bf16 [4][2048][2048]

  zero_out<<<dim3(4096), dim3(256), 0, stream>>>(out);
  convert_f32_bf16<<<dim3(4096), dim3(256), 0, stream>>>(x, xb);
  build_wT<<<dim3(6144), dim3(256), 0, stream>>>(wq, wk, wv, wbT);
  qkv_gemm<<<dim3(768), dim3(256), 0, stream>>>(xb, wbT, bq, bk, bv, qb, kb, vb);
  transpose_v<<<dim3(8, 32, 4), dim3(256), 0, stream>>>(vb, vtb);
  scores_gemm<<<dim3(16, 32, 4), dim3(256), 0, stream>>>(qb, kb, sc);
  softmax_rows<<<dim3(2048, 4), dim3(256), 0, stream>>>(sc);
  pv_gemm<<<dim3(4, 128, 4), dim3(256), 0, stream>>>(sc, vtb, out);
}